// Round 1
// baseline (277.179 us; speedup 1.0000x reference)
//
#include <hip/hip_runtime.h>

#define EPS_C 0.05f
#define BLOCK 256
#define ITEMS 16
#define CHUNK (BLOCK * ITEMS) /* 4096 */
#define SB 1024               /* scan-sums block */

// Build the 6-entry change table into LDS (thread 0 only; caller syncs).
__device__ __forceinline__ void build_table(const float* bd_p, const float* d_p,
                                            const float* s_p, const float* inc_p,
                                            const float* bi_p, float* cs) {
  if (threadIdx.x == 0) {
    float bd = *bd_p, d = *d_p, s = *s_p, inc = *inc_p, bi = *bi_p;
    cs[0] = 0.0f;                                       // cat 0 (unused)
    cs[1] = fminf(bd, fminf(0.0f, d)) - EPS_C;          // big decrease
    cs[2] = fminf(fmaxf(d, bd + EPS_C), -EPS_C);        // decrease (clip)
    cs[3] = s;                                          // same
    cs[4] = fminf(fmaxf(inc, EPS_C), bi - EPS_C);       // increase (clip)
    cs[5] = fmaxf(bi, fmaxf(0.0f, inc) + EPS_C);        // big increase
    cs[6] = 0.0f; cs[7] = 0.0f;
  }
}

// Pass 1: per-block sum of table[ann[k]] over CHUNK elements.
__global__ __launch_bounds__(BLOCK) void k_reduce(
    const int* __restrict__ ann, const float* bd, const float* d,
    const float* s, const float* inc, const float* bi,
    float* __restrict__ blockSums) {
  __shared__ float cs[8];
  __shared__ float wsum[BLOCK / 64];
  build_table(bd, d, s, inc, bi, cs);
  __syncthreads();

  const int b = blockIdx.x;
  const int t = threadIdx.x;
  const int4* in4 = (const int4*)(ann + (size_t)b * CHUNK);

  float sum = 0.0f;
#pragma unroll
  for (int i = 0; i < ITEMS / 4; ++i) {
    int4 v = in4[t * (ITEMS / 4) + i];
    sum += cs[v.x] + cs[v.y] + cs[v.z] + cs[v.w];
  }
#pragma unroll
  for (int off = 32; off >= 1; off >>= 1) sum += __shfl_down(sum, off, 64);

  const int lane = t & 63, wid = t >> 6;
  if (lane == 0) wsum[wid] = sum;
  __syncthreads();
  if (t == 0) {
    float tot = 0.0f;
#pragma unroll
    for (int i = 0; i < BLOCK / 64; ++i) tot += wsum[i];
    blockSums[b] = tot;
  }
}

// Pass 2: exclusive scan of nb (<= SB*8) block sums in one block.
__global__ __launch_bounds__(SB) void k_scan_sums(
    const float* __restrict__ sums, float* __restrict__ offs, int nb) {
  __shared__ float wsum[SB / 64];
  const int t = threadIdx.x;
  const int lane = t & 63, wid = t >> 6;

  float pre[8];
  float run = 0.0f;
#pragma unroll
  for (int i = 0; i < 8; ++i) {
    int idx = t * 8 + i;
    float v = (idx < nb) ? sums[idx] : 0.0f;
    pre[i] = run;
    run += v;
  }
  float x = run;  // inclusive wave scan of thread totals
#pragma unroll
  for (int off = 1; off < 64; off <<= 1) {
    float y = __shfl_up(x, off, 64);
    if (lane >= off) x += y;
  }
  if (lane == 63) wsum[wid] = x;
  __syncthreads();
  float wexcl = 0.0f;
  for (int i = 0; i < wid; ++i) wexcl += wsum[i];
  float texcl = wexcl + (x - run);  // exclusive prefix for this thread
#pragma unroll
  for (int i = 0; i < 8; ++i) {
    int idx = t * 8 + i;
    if (idx < nb) offs[idx] = texcl + pre[i];
  }
}

// Pass 3: per-block exclusive scan + write. Block b produces out[j] for
// j in [b*CHUNK, (b+1)*CHUNK): out[j] = origin + offs[b] + sum(ann[b*CHUNK..j-1]).
// Last thread of last block also writes out[N].
__global__ __launch_bounds__(BLOCK) void k_scan(
    const int* __restrict__ ann, const float* origin, const float* bd,
    const float* d, const float* s, const float* inc, const float* bi,
    const float* __restrict__ offs, float* __restrict__ out, int nb) {
  __shared__ float cs[8];
  __shared__ float wsum[BLOCK / 64];
  build_table(bd, d, s, inc, bi, cs);
  __syncthreads();

  const int b = blockIdx.x;
  const int t = threadIdx.x;
  const size_t base = (size_t)b * CHUNK;
  const int4* in4 = (const int4*)(ann + base);

  float vals[ITEMS];
#pragma unroll
  for (int i = 0; i < ITEMS / 4; ++i) {
    int4 v = in4[t * (ITEMS / 4) + i];
    vals[i * 4 + 0] = cs[v.x];
    vals[i * 4 + 1] = cs[v.y];
    vals[i * 4 + 2] = cs[v.z];
    vals[i * 4 + 3] = cs[v.w];
  }

  float pre[ITEMS];
  float run = 0.0f;
#pragma unroll
  for (int i = 0; i < ITEMS; ++i) { pre[i] = run; run += vals[i]; }

  float x = run;  // inclusive wave scan of per-thread totals
  const int lane = t & 63, wid = t >> 6;
#pragma unroll
  for (int off = 1; off < 64; off <<= 1) {
    float y = __shfl_up(x, off, 64);
    if (lane >= off) x += y;
  }
  if (lane == 63) wsum[wid] = x;
  __syncthreads();
  float wexcl = 0.0f;
  for (int i = 0; i < wid; ++i) wexcl += wsum[i];

  const float off0 = *origin + offs[b] + wexcl + (x - run);

  float4* out4 = (float4*)(out + base);
#pragma unroll
  for (int i = 0; i < ITEMS / 4; ++i) {
    float4 o;
    o.x = off0 + pre[i * 4 + 0];
    o.y = off0 + pre[i * 4 + 1];
    o.z = off0 + pre[i * 4 + 2];
    o.w = off0 + pre[i * 4 + 3];
    out4[t * (ITEMS / 4) + i] = o;
  }
  if (b == nb - 1 && t == BLOCK - 1)
    out[(size_t)nb * CHUNK] = off0 + run;  // out[N] = origin + total sum
}

extern "C" void kernel_launch(void* const* d_in, const int* in_sizes, int n_in,
                              void* d_out, int out_size, void* d_ws, size_t ws_size,
                              hipStream_t stream) {
  const int*   ann    = (const int*)d_in[0];
  const float* origin = (const float*)d_in[1];
  const float* bd     = (const float*)d_in[2];
  const float* dw     = (const float*)d_in[3];
  const float* sw     = (const float*)d_in[4];
  const float* inc    = (const float*)d_in[5];
  const float* bi     = (const float*)d_in[6];
  float* out = (float*)d_out;

  const int N  = in_sizes[0];       // 2^25, divisible by CHUNK
  const int nb = N / CHUNK;         // 8192

  float* blockSums = (float*)d_ws;  // nb floats
  float* blockOffs = blockSums + nb;

  k_reduce<<<nb, BLOCK, 0, stream>>>(ann, bd, dw, sw, inc, bi, blockSums);
  k_scan_sums<<<1, SB, 0, stream>>>(blockSums, blockOffs, nb);
  k_scan<<<nb, BLOCK, 0, stream>>>(ann, origin, bd, dw, sw, inc, bi,
                                   blockOffs, out, nb);
}